// Round 6
// baseline (316.288 us; speedup 1.0000x reference)
//
#include <hip/hip_runtime.h>
#include <hip/hip_bf16.h>
#include <math.h>

#define PI_D 3.14159265358979323846

typedef __attribute__((ext_vector_type(8))) short bf16x8;
typedef __attribute__((ext_vector_type(4))) float f32x4;
typedef __attribute__((ext_vector_type(4))) unsigned int u32x4;

// ---------------- workspace layout (float offsets) ----------------
#define OFF_SCAL   0u                 // 4 floats
#define OFF_W2B    4u                 // 2*128*128 bf16 = 16384 floats [i][o'][k]
#define OFF_BF     16388u             // Bfrag: 8r*55c*4kb*128o*8j bf16 = 901120 floats
#define OFF_XOUTB  917508u            // 8*8*2304*128 bf16 = 9437184 floats
#define OFF_A0     10354692u          // 8*4*2304
#define OFF_A1     10428420u          // 8*8*2304
#define OFF_Z0     10575876u          // 8*4*4*2304
#define OFF_Z1     10870788u          // 8*4*8*2304 -> ends 11460612 floats = 45.8 MB

#define NS33 42                       // K-steps for 33-kernel (rows padded to 40 taps)
#define NS17 13                       // K-steps for 17-kernel (rows padded to 24 taps)

__device__ __forceinline__ float off_r(int r) {
  int m = (r <= 4) ? r : r - 8;
  return (float)(PI_D / 4.0) * (float)m;
}
__device__ __forceinline__ float lrelu_f(float v) { return (v >= 0.f) ? v : 0.01f * v; }
__device__ __forceinline__ short f2bf(float f) {
  __bf16 h = (__bf16)f;
  return __builtin_bit_cast(short, h);
}

// ---------------- fused prep: scalars + w2 cast + rotation/B-frag ----------------
__global__ void k_prep(const float* __restrict__ kw, const float* __restrict__ gk,
                       const float* __restrict__ rw, const float* __restrict__ gr,
                       const float* __restrict__ w0, const float* __restrict__ w1,
                       const float* __restrict__ w2, float* __restrict__ scal,
                       short* __restrict__ w2b, short* __restrict__ bfrag) {
  int t = blockIdx.x * blockDim.x + threadIdx.x;
  if (t == 0) {
    float a0 = (kw[0] + gk[0]) * 0.1f, a1 = (kw[1] + gk[1]) * 0.1f;
    float m = fmaxf(a0, a1);
    float e0 = expf(a0 - m), e1 = expf(a1 - m), inv = 1.f / (e0 + e1);
    scal[0] = e0 * inv; scal[1] = e1 * inv;
    float b0 = (rw[0] + gr[0]) * 0.1f, b1 = (rw[1] + gr[1]) * 0.1f;
    m = fmaxf(b0, b1);
    e0 = expf(b0 - m); e1 = expf(b1 - m); inv = 1.f / (e0 + e1);
    scal[2] = e0 * inv; scal[3] = e1 * inv;
  }
  if (t < 2 * 128 * 128) w2b[t] = f2bf(w2[t]);   // [i][o'][k], k contiguous
  // ---- B-fragment build (fused rotation) ----
  int o = t & 127;
  int q = t >> 7;
  int kb = q & 3; q >>= 2;
  int c = q % 55; int r = q / 55;
  float theta = (float)(PI_D / 4.0) * (float)r;
  float cth = cosf(theta), sth = sinf(theta);
  short out[8];
#pragma unroll
  for (int j = 0; j < 8; ++j) {
    float val = 0.f;
    int kk, k, dy, dx;
    const float* wsrc;
    if (c < NS33) { kk = 32 * c + 8 * kb + j; k = 33; dy = kk / 40; dx = kk - 40 * dy; wsrc = w1; }
    else          { kk = 32 * (c - NS33) + 8 * kb + j; k = 17; dy = kk / 24; dx = kk - 24 * dy; wsrc = w0; }
    if (dy < k && dx < k) {
      int kk2 = k * k;
      const float* wo = wsrc + o * kk2;
      float cy = (2.0f * (float)dy + 1.0f) / (float)k - 1.0f;
      float cx = (2.0f * (float)dx + 1.0f) / (float)k - 1.0f;
      float sx = cth * cx - sth * cy;
      float sy = sth * cx + cth * cy;
      float fx = ((sx + 1.0f) * (float)k - 1.0f) * 0.5f;
      float fy = ((sy + 1.0f) * (float)k - 1.0f) * 0.5f;
      float x0f = floorf(fx), y0f = floorf(fy);
      int x0 = (int)x0f, y0 = (int)y0f;
      float wx1 = fx - x0f, wy1 = fy - y0f;
      float acc = 0.f;
#define CORNER(Y, X, CW) { int yy = (Y), xx = (X); \
      if (yy >= 0 && yy < k && xx >= 0 && xx < k) acc += wo[yy * k + xx] * (CW); }
      CORNER(y0,     x0,     (1.f - wy1) * (1.f - wx1));
      CORNER(y0,     x0 + 1, (1.f - wy1) * wx1);
      CORNER(y0 + 1, x0,     wy1 * (1.f - wx1));
      CORNER(y0 + 1, x0 + 1, wy1 * wx1);
#undef CORNER
      val = acc;
    }
    out[j] = f2bf(val);
  }
  *(bf16x8*)(bfrag + (size_t)t * 8) =
      (bf16x8){out[0], out[1], out[2], out[3], out[4], out[5], out[6], out[7]};
}

// ---------------- MFMA implicit-GEMM conv ----------------
// bf16 LDS tile, two copies (copyB = shift-by-1-pixel). Fragments are mapped by
// PIXEL PARITY (frag0 = even pixels base+2*ln, frag1 = odd): every ds_read
// instruction addresses a single copy at even bf16 index -> 4B-aligned
// ds_read_b32 x4, lane dword-stride 1, span < 32 banks -> conflict-free.
#define TDW 3080                      // 35 rows x 88 cols (pixels)
#define SHW 1544                      // copyB dword offset (copyA = 1540 dwords)
__global__ __launch_bounds__(256, 4) void k_conv_mfma(
    const float* __restrict__ x, const short* __restrict__ bfrag,
    const float* __restrict__ b17, const float* __restrict__ b33,
    const float* __restrict__ scal, short* __restrict__ xoutb) {
  __shared__ unsigned int lds[SHW + 1540];
  unsigned short* lA = (unsigned short*)lds;              // pixel i at idx i
  unsigned short* lB = (unsigned short*)(lds + SHW);      // pixel i+1 at idx i
  int blk = blockIdx.x;
  int pt = blk % 36; int t2 = blk / 36; int r = t2 & 7, b = t2 >> 3;
  int p0 = pt * 64;
  int ybase = p0 / 48;
  int tid = threadIdx.x;
  for (int idx = tid; idx < TDW; idx += 256) {
    int ty = idx / 88, tx = idx - ty * 88;
    int gy = ybase + ty - 8, gx = tx - 8;
    float v = 0.f;
    if (gy >= 0 && gy < 64 && gx >= 0 && gx < 64) v = x[(b * 64 + gy) * 64 + gx];
    unsigned short h = (unsigned short)f2bf(v);
    lA[idx] = h;
    if (idx > 0) lB[idx - 1] = h;
  }
  if (tid == 0) lB[TDW - 1] = 0;
  __syncthreads();

  int lane = tid & 63, w = tid >> 6;
  int wm = w >> 1, wn = w & 1;
  int kc = lane >> 4;
  int ln = lane & 15;
  int mloc[2];
#pragma unroll
  for (int mf = 0; mf < 2; ++mf) {
    int p = p0 + wm * 32 + mf + 2 * ln;     // frag mf covers parity-mf pixels
    int ym = p / 48, xm = p - ym * 48;
    mloc[mf] = (ym - ybase) * 88 + xm;      // parity(mloc) == parity(p) == mf
  }
  const short* bb = bfrag + (size_t)r * (55 * 4 * 128 * 8);
  int nb0 = wn * 64;

  f32x4 acc33[2][4];
#pragma unroll
  for (int mf = 0; mf < 2; ++mf)
#pragma unroll
    for (int nf = 0; nf < 4; ++nf) acc33[mf][nf] = (f32x4){0.f, 0.f, 0.f, 0.f};

#define LOADB(dst, cg)                                                          \
  {                                                                             \
    _Pragma("unroll")                                                           \
    for (int nf = 0; nf < 4; ++nf)                                              \
      dst[nf] = *(const bf16x8*)(bb + ((size_t)((cg)*4 + kc) * 128 + nb0 + nf * 16 + ln) * 8); \
  }
#define READA(dst, mf, vv)                                                      \
  {                                                                             \
    int bd_ = ((vv) >> 1) + ((mf) ? SHW : 0);                                   \
    u32x4 uv_ = {lds[bd_], lds[bd_ + 1], lds[bd_ + 2], lds[bd_ + 3]};           \
    dst = __builtin_bit_cast(bf16x8, uv_);                                      \
  }

  // ---- phase 1: 33x33 kernel (rows padded to 40 taps, 42 K-steps) ----
  {
    int dxb = 8 * kc;
    int off = dxb;
    bf16x8 bc[4], bn[4];
    LOADB(bc, 0);
    for (int c = 0; c < NS33; ++c) {
      if (c + 1 < NS33) LOADB(bn, c + 1);
      bf16x8 a0, a1;
      READA(a0, 0, mloc[0] + off);
      READA(a1, 1, mloc[1] + off);
#pragma unroll
      for (int nf = 0; nf < 4; ++nf) {
        acc33[0][nf] = __builtin_amdgcn_mfma_f32_16x16x32_bf16(a0, bc[nf], acc33[0][nf], 0, 0, 0);
        acc33[1][nf] = __builtin_amdgcn_mfma_f32_16x16x32_bf16(a1, bc[nf], acc33[1][nf], 0, 0, 0);
      }
#pragma unroll
      for (int nf = 0; nf < 4; ++nf) bc[nf] = bn[nf];
      int nd = dxb + 32;
      int wr = (nd >= 40);
      dxb = wr ? nd - 40 : nd;
      off += wr ? 80 : 32;
    }
  }

  // ---- phase 2: 17x17 kernel (rows padded to 24 taps, 13 K-steps) ----
  f32x4 acc17[2][4];
#pragma unroll
  for (int mf = 0; mf < 2; ++mf)
#pragma unroll
    for (int nf = 0; nf < 4; ++nf) acc17[mf][nf] = (f32x4){0.f, 0.f, 0.f, 0.f};
  {
    int t8 = 8 * kc;
    int dy0 = t8 / 24;
    int dxb = t8 - 24 * dy0;
    int off = (8 + dy0) * 88 + 8 + dxb;
    for (int c = 0; c < NS17; ++c) {
      bf16x8 bc[4];
      LOADB(bc, NS33 + c);
      bf16x8 a0, a1;
      READA(a0, 0, mloc[0] + off);
      READA(a1, 1, mloc[1] + off);
#pragma unroll
      for (int nf = 0; nf < 4; ++nf) {
        acc17[0][nf] = __builtin_amdgcn_mfma_f32_16x16x32_bf16(a0, bc[nf], acc17[0][nf], 0, 0, 0);
        acc17[1][nf] = __builtin_amdgcn_mfma_f32_16x16x32_bf16(a1, bc[nf], acc17[1][nf], 0, 0, 0);
      }
      int nd = dxb + 8;
      int wr = (nd >= 24);
      dxb = wr ? nd - 24 : nd;
      off += wr ? 160 : 96;
    }
  }
#undef LOADB
#undef READA

  // ---- epilogue: bias, lrelu, alpha-combine, bf16 store ----
  float a0s = scal[0], a1s = scal[1];
  int dq = lane >> 4;
#pragma unroll
  for (int nf = 0; nf < 4; ++nf) {
    int n = nb0 + nf * 16 + ln;
    float bb17 = b17[n], bb33 = b33[n];
#pragma unroll
    for (int mf = 0; mf < 2; ++mf) {
#pragma unroll
      for (int i = 0; i < 4; ++i) {
        int m = wm * 32 + mf + 8 * dq + 2 * i;   // pixel = base + mf + 2*(4*dq+i)
        float v = a0s * lrelu_f(acc17[mf][nf][i] + bb17)
                + a1s * lrelu_f(acc33[mf][nf][i] + bb33);
        xoutb[((size_t)(b * 8 + r) * 2304 + p0 + m) * 128 + n] = f2bf(v);
      }
    }
  }
}

// ---------------- MFMA 1x1 conv + fused heads, coalesced stores via LDS ----------------
// blocks [0,1152): i=0 (nR=4, rstep=2); [1152,3456): i=1 (nR=8, rstep=1)
__global__ __launch_bounds__(256, 8) void k_pw_mfma(
    const short* __restrict__ xoutb, const short* __restrict__ w2b_,
    const float* __restrict__ b2_, const float* __restrict__ wa_,
    const float* __restrict__ ba_, const float* __restrict__ wz_,
    const float* __restrict__ bz_,
    float* __restrict__ a0buf, float* __restrict__ z0buf,
    float* __restrict__ a1buf, float* __restrict__ z1buf) {
  __shared__ float sA[64];
  __shared__ float sZ[4][64];
  int blk = blockIdx.x;
  int i1 = (blk >= 1152);
  int lblk = i1 ? blk - 1152 : blk;
  int nR = i1 ? 8 : 4, rstep = i1 ? 1 : 2;
  const short* w2b = w2b_ + (i1 ? 128 * 128 : 0);
  const float* b2 = b2_ + (i1 ? 128 : 0);
  const float* wa = wa_ + (i1 ? 128 : 0);
  const float* ba = ba_ + i1;
  const float* wz = wz_ + (i1 ? 512 : 0);
  const float* bz = bz_ + (i1 ? 4 : 0);
  float* attn_out = i1 ? a1buf : a0buf;
  float* z_out = i1 ? z1buf : z0buf;

  int pblk = lblk % 36;
  int t = lblk / 36;
  int rl = t % nR;
  int b = t / nR;
  int pix0 = pblk * 64;
  int tid = threadIdx.x;
  int lane = tid & 63, w = tid >> 6;
  int kc = lane >> 4, ln = lane & 15;
  int pwave = pix0 + w * 16;
  const short* arow = xoutb + ((size_t)(b * 8 + rl * rstep) * 2304 + pwave) * 128;

  f32x4 acc[8];
#pragma unroll
  for (int nf = 0; nf < 8; ++nf) acc[nf] = (f32x4){0.f, 0.f, 0.f, 0.f};
#pragma unroll
  for (int s = 0; s < 4; ++s) {
    bf16x8 a = *(const bf16x8*)(arow + ln * 128 + s * 32 + kc * 8);
#pragma unroll
    for (int nf = 0; nf < 8; ++nf) {
      bf16x8 bv = *(const bf16x8*)(w2b + (nf * 16 + ln) * 128 + s * 32 + kc * 8);
      acc[nf] = __builtin_amdgcn_mfma_f32_16x16x32_bf16(a, bv, acc[nf], 0, 0, 0);
    }
  }

  float attn_acc[4] = {0.f, 0.f, 0.f, 0.f};
  float zacc[4][4];
#pragma unroll
  for (int j = 0; j < 4; ++j)
#pragma unroll
    for (int q = 0; q < 4; ++q) zacc[j][q] = 0.f;
#pragma unroll
  for (int nf = 0; nf < 8; ++nf) {
    int n = nf * 16 + ln;
    float bb2 = b2[n];
    float wan = wa[n];
    float wz0 = wz[n], wz1 = wz[128 + n], wz2 = wz[256 + n], wz3 = wz[384 + n];
#pragma unroll
    for (int q = 0; q < 4; ++q) {
      float h = lrelu_f(acc[nf][q] + bb2);
      attn_acc[q] = fmaf(wan, h, attn_acc[q]);
      zacc[0][q] = fmaf(wz0, h, zacc[0][q]);
      zacc[1][q] = fmaf(wz1, h, zacc[1][q]);
      zacc[2][q] = fmaf(wz2, h, zacc[2][q]);
      zacc[3][q] = fmaf(wz3, h, zacc[3][q]);
    }
  }
#pragma unroll
  for (int off = 1; off < 16; off <<= 1) {
#pragma unroll
    for (int q = 0; q < 4; ++q) {
      attn_acc[q] += __shfl_xor(attn_acc[q], off);
#pragma unroll
      for (int j = 0; j < 4; ++j) zacc[j][q] += __shfl_xor(zacc[j][q], off);
    }
  }
  if (ln == 0) {
    float ba0 = ba[0];
#pragma unroll
    for (int q = 0; q < 4; ++q) {
      int px = w * 16 + kc * 4 + q;          // pixel within block
      sA[px] = attn_acc[q] + ba0;
#pragma unroll
      for (int j = 0; j < 4; ++j) sZ[j][px] = zacc[j][q] + bz[j];
    }
  }
  __syncthreads();
  int px = tid & 63, jj = tid >> 6;
  if (jj == 0)
    attn_out[((size_t)b * nR + rl) * 2304 + pix0 + px] = sA[px];
  z_out[(((size_t)b * 4 + jj) * nR + rl) * 2304 + pix0 + px] = sZ[jj][px];
}

// ---------------- attn scatter + p_r; also p_r / offsets outputs ----------------
__global__ void k_attn_combine(const float* __restrict__ a0buf, const float* __restrict__ a1buf,
                               const float* __restrict__ scal, float* __restrict__ out0,
                               float* __restrict__ out2, float* __restrict__ out4) {
  int idx = blockIdx.x * blockDim.x + threadIdx.x;
  if (idx < 8) {
    float off = off_r(idx);
    out4[idx] = off;
    float q = off / (float)PI_D;
    out2[idx] = -0.5f * q * q - logf((float)PI_D) - 0.5f * logf(2.0f * (float)PI_D);
  }
  if (idx >= 147456) return;
  int pix = idx % 2304;
  int t = idx / 2304;
  int r = t & 7, b = t >> 3;
  float v = scal[3] * a1buf[idx];
  if (!(r & 1)) v += scal[2] * a0buf[((size_t)b * 4 + (r >> 1)) * 2304 + pix];
  float q = off_r(r) / (float)PI_D;
  v += -0.5f * q * q - logf((float)PI_D) - 0.5f * logf(2.0f * (float)PI_D);
  out0[idx] = v;
}

// ---------------- per-batch softmax / log_softmax over 18432 ----------------
__global__ __launch_bounds__(1024) void k_softmax(const float* __restrict__ out0,
                                                  const float* __restrict__ g,
                                                  float* __restrict__ out1,
                                                  float* __restrict__ out3) {
  int b = blockIdx.x;
  int tid = threadIdx.x;
  const float* v = out0 + (size_t)b * 18432;
  const float* gb = g + (size_t)b * 18432;
  float vl[18], gl[18];
  float m1 = -1e30f, m2 = -1e30f;
#pragma unroll
  for (int t = 0; t < 18; ++t) {
    float vv = v[tid + (t << 10)];
    float gg = gb[tid + (t << 10)];
    vl[t] = vv;
    gl[t] = vv + gg;
    m1 = fmaxf(m1, vv);
    m2 = fmaxf(m2, gl[t]);
  }
  __shared__ float red[32];
  for (int off = 32; off > 0; off >>= 1) {
    m1 = fmaxf(m1, __shfl_xor(m1, off));
    m2 = fmaxf(m2, __shfl_xor(m2, off));
  }
  int wid = tid >> 6, lane = tid & 63;
  if (lane == 0) { red[wid] = m1; red[wid + 16] = m2; }
  __syncthreads();
  float M1 = red[0], M2 = red[16];
#pragma unroll
  for (int w = 1; w < 16; ++w) { M1 = fmaxf(M1, red[w]); M2 = fmaxf(M2, red[w + 16]); }
  __syncthreads();
  float s1 = 0.f, s2 = 0.f;
#pragma unroll
  for (int t = 0; t < 18; ++t) { s1 += expf(vl[t] - M1); s2 += expf(gl[t] - M2); }
  for (int off = 32; off > 0; off >>= 1) {
    s1 += __shfl_xor(s1, off);
    s2 += __shfl_xor(s2, off);
  }
  if (lane == 0) { red[wid] = s1; red[wid + 16] = s2; }
  __syncthreads();
  float S1 = 0.f, S2 = 0.f;
#pragma unroll
  for (int w = 0; w < 16; ++w) { S1 += red[w]; S2 += red[w + 16]; }
  float lse = M1 + logf(S1);
  float inv2 = 1.0f / S2;
  float* o1 = out1 + (size_t)b * 18432;
  float* o3 = out3 + (size_t)b * 18432;
#pragma unroll
  for (int t = 0; t < 18; ++t) {
    o1[tid + (t << 10)] = vl[t] - lse;
    o3[tid + (t << 10)] = expf(gl[t] - M2) * inv2;
  }
}

// ---------------- z scatter + theta ----------------
__global__ void k_ztheta(const float* __restrict__ z0buf, const float* __restrict__ z1buf,
                         const float* __restrict__ scal, float* __restrict__ out5,
                         float* __restrict__ out6) {
  int idx = blockIdx.x * blockDim.x + threadIdx.x;
  if (idx >= 589824) return;
  int pix = idx % 2304;
  int t = idx / 2304;
  int r = t & 7;
  t >>= 3;
  int c = t & 3;
  int b = t >> 2;
  float v = scal[3] * z1buf[idx];
  if (!(r & 1)) v += scal[2] * z0buf[(((size_t)b * 4 + c) * 4 + (r >> 1)) * 2304 + pix];
  out6[idx] = v;
  if (c == 0)      out5[(((size_t)b * 2 + 0) * 8 + r) * 2304 + pix] = v + off_r(r);
  else if (c == 1) out5[(((size_t)b * 2 + 1) * 8 + r) * 2304 + pix] = v;
}

// ---------------- launcher ----------------
extern "C" void kernel_launch(void* const* d_in, const int* in_sizes, int n_in,
                              void* d_out, int out_size, void* d_ws, size_t ws_size,
                              hipStream_t stream) {
  const float* x   = (const float*)d_in[0];
  const float* ksz = (const float*)d_in[1];
  const float* rdw = (const float*)d_in[2];
  const float* w0  = (const float*)d_in[3];
  const float* b0  = (const float*)d_in[4];
  const float* w1  = (const float*)d_in[5];
  const float* b1  = (const float*)d_in[6];
  const float* w2  = (const float*)d_in[7];
  const float* b2  = (const float*)d_in[8];
  const float* wa  = (const float*)d_in[9];
  const float* ba  = (const float*)d_in[10];
  const float* wz  = (const float*)d_in[11];
  const float* bz  = (const float*)d_in[12];
  const float* gks = (const float*)d_in[13];
  const float* grd = (const float*)d_in[14];
  const float* gat = (const float*)d_in[15];
  float* out = (float*)d_out;
  float* ws  = (float*)d_ws;

  float* scal = ws + OFF_SCAL;
  short* w2b  = (short*)(ws + OFF_W2B);
  short* bfr  = (short*)(ws + OFF_BF);
  short* xoutb = (short*)(ws + OFF_XOUTB);
  float* a0b  = ws + OFF_A0;
  float* a1b  = ws + OFF_A1;
  float* z0b  = ws + OFF_Z0;
  float* z1b  = ws + OFF_Z1;

  float* out0 = out;
  float* out1 = out + 147456;
  float* out2 = out + 294912;
  float* out3 = out + 294920;
  float* out4 = out + 442376;
  float* out5 = out + 442384;
  float* out6 = out + 737296;

  k_prep<<<880, 256, 0, stream>>>(ksz, gks, rdw, grd, w0, w1, w2, scal, w2b, bfr);
  k_conv_mfma<<<2304, 256, 0, stream>>>(x, bfr, b0, b1, scal, xoutb);
  k_pw_mfma<<<3456, 256, 0, stream>>>(xoutb, w2b, b2, wa, ba, wz, bz,
                                      a0b, z0b, a1b, z1b);
  k_attn_combine<<<576, 256, 0, stream>>>(a0b, a1b, scal, out0, out2, out4);
  k_softmax<<<8, 1024, 0, stream>>>(out0, gat, out1, out3);
  k_ztheta<<<2304, 256, 0, stream>>>(z0b, z1b, scal, out5, out6);
}

// Round 8
// 267.494 us; speedup vs baseline: 1.1824x; 1.1824x over previous
//
#include <hip/hip_runtime.h>
#include <hip/hip_bf16.h>
#include <math.h>

#define PI_D 3.14159265358979323846

typedef __attribute__((ext_vector_type(8))) short bf16x8;
typedef __attribute__((ext_vector_type(4))) float f32x4;
typedef __attribute__((ext_vector_type(4))) unsigned int u32x4;

// ---------------- workspace layout (float offsets) ----------------
#define OFF_SCAL   0u                 // 4 floats
#define OFF_W0T    4u                 // 289*128
#define OFF_W1T    36996u             // 1089*128
#define OFF_W2B    176388u            // 2*128*128 bf16 = 16384 floats [i][o'][k]
#define OFF_BF     192772u            // Bfrag: 8r*55c*4kb*128o*8j bf16 = 901120 floats
#define OFF_XOUTB  1093892u           // 8*8*2304*128 bf16 = 9437184 floats (18.9M shorts)
#define OFF_A0     10531076u          // 8*4*2304
#define OFF_A1     10604804u          // 8*8*2304
#define OFF_Z0     10752260u          // 8*4*4*2304
#define OFF_Z1     11047172u          // 8*4*8*2304 -> ends 11636996 floats = 46.5 MB

#define NS33 42                       // K-steps for 33-kernel (rows padded to 40 taps)
#define NS17 13                       // K-steps for 17-kernel (rows padded to 24 taps)

__device__ __forceinline__ float off_r(int r) {
  int m = (r <= 4) ? r : r - 8;
  return (float)(PI_D / 4.0) * (float)m;
}
__device__ __forceinline__ float lrelu_f(float v) { return (v >= 0.f) ? v : 0.01f * v; }
__device__ __forceinline__ short f2bf(float f) {
  __bf16 h = (__bf16)f;
  return __builtin_bit_cast(short, h);
}

// ---------------- prep1: scalars + coalesced transposes + w2 cast ----------------
__global__ void k_prep1(const float* __restrict__ kw, const float* __restrict__ gk,
                        const float* __restrict__ rw, const float* __restrict__ gr,
                        const float* __restrict__ w0, const float* __restrict__ w1,
                        const float* __restrict__ w2, float* __restrict__ scal,
                        float* __restrict__ w0T, float* __restrict__ w1T,
                        short* __restrict__ w2b) {
  int idx = blockIdx.x * blockDim.x + threadIdx.x;
  if (idx == 0) {
    float a0 = (kw[0] + gk[0]) * 0.1f, a1 = (kw[1] + gk[1]) * 0.1f;
    float m = fmaxf(a0, a1);
    float e0 = expf(a0 - m), e1 = expf(a1 - m), inv = 1.f / (e0 + e1);
    scal[0] = e0 * inv; scal[1] = e1 * inv;
    float b0 = (rw[0] + gr[0]) * 0.1f, b1 = (rw[1] + gr[1]) * 0.1f;
    m = fmaxf(b0, b1);
    e0 = expf(b0 - m); e1 = expf(b1 - m); inv = 1.f / (e0 + e1);
    scal[2] = e0 * inv; scal[3] = e1 * inv;
  }
  if (idx < 289 * 128) {
    int o = idx & 127, pos = idx >> 7;
    w0T[pos * 128 + o] = w0[o * 289 + pos];
    return;
  }
  idx -= 289 * 128;
  if (idx < 1089 * 128) {
    int o = idx & 127, pos = idx >> 7;
    w1T[pos * 128 + o] = w1[o * 1089 + pos];
    return;
  }
  idx -= 1089 * 128;
  if (idx < 2 * 128 * 128) w2b[idx] = f2bf(w2[idx]);   // [i][o'][k]
}

// ---------------- prep2: fused rotation + B-fragment build (coalesced) ----------------
__global__ void k_prep2(const float* __restrict__ w0T, const float* __restrict__ w1T,
                        short* __restrict__ bfrag) {
  int t = blockIdx.x * blockDim.x + threadIdx.x;   // 225280 threads
  int o = t & 127;
  int q = t >> 7;
  int kb = q & 3; q >>= 2;
  int c = q % 55; int r = q / 55;
  float theta = (float)(PI_D / 4.0) * (float)r;
  float cth = cosf(theta), sth = sinf(theta);
  short out[8];
#pragma unroll
  for (int j = 0; j < 8; ++j) {
    float val = 0.f;
    int kk, k, dy, dx;
    const float* wT;
    if (c < NS33) { kk = 32 * c + 8 * kb + j; k = 33; dy = kk / 40; dx = kk - 40 * dy; wT = w1T; }
    else          { kk = 32 * (c - NS33) + 8 * kb + j; k = 17; dy = kk / 24; dx = kk - 24 * dy; wT = w0T; }
    if (dy < k && dx < k) {
      float cy = (2.0f * (float)dy + 1.0f) / (float)k - 1.0f;
      float cx = (2.0f * (float)dx + 1.0f) / (float)k - 1.0f;
      float sx = cth * cx - sth * cy;
      float sy = sth * cx + cth * cy;
      float fx = ((sx + 1.0f) * (float)k - 1.0f) * 0.5f;
      float fy = ((sy + 1.0f) * (float)k - 1.0f) * 0.5f;
      float x0f = floorf(fx), y0f = floorf(fy);
      int x0 = (int)x0f, y0 = (int)y0f;
      float wx1 = fx - x0f, wy1 = fy - y0f;
      float acc = 0.f;
#define CORNER(Y, X, CW) { int yy = (Y), xx = (X); \
      if (yy >= 0 && yy < k && xx >= 0 && xx < k) acc += wT[(yy * k + xx) * 128 + o] * (CW); }
      CORNER(y0,     x0,     (1.f - wy1) * (1.f - wx1));
      CORNER(y0,     x0 + 1, (1.f - wy1) * wx1);
      CORNER(y0 + 1, x0,     wy1 * (1.f - wx1));
      CORNER(y0 + 1, x0 + 1, wy1 * wx1);
#undef CORNER
      val = acc;
    }
    out[j] = f2bf(val);
  }
  *(bf16x8*)(bfrag + (size_t)t * 8) =
      (bf16x8){out[0], out[1], out[2], out[3], out[4], out[5], out[6], out[7]};
}

// ---------------- MFMA implicit-GEMM conv ----------------
// bf16 LDS tile, two copies (copyB = shift-by-1-pixel), parity-mapped fragments
// (conflict-free reads). Epilogue: stage 64x128 bf16 output in LDS (XOR-swizzled
// on dword bits 3,4 by kc) then copy out linearly -> full-line HBM writes, no RMW.
#define TDW 3080                      // 35 rows x 88 cols (pixels)
#define SHW 1544                      // copyB dword offset (copyA = 1540 dwords)
__global__ __launch_bounds__(256, 4) void k_conv_mfma(
    const float* __restrict__ x, const short* __restrict__ bfrag,
    const float* __restrict__ b17, const float* __restrict__ b33,
    const float* __restrict__ scal, short* __restrict__ xoutb) {
  __shared__ __align__(16) unsigned int lds[4352];        // 17408 B (stage needs 12336)
  unsigned short* lA = (unsigned short*)lds;              // pixel i at idx i
  unsigned short* lB = (unsigned short*)(lds + SHW);      // pixel i+1 at idx i
  int blk = blockIdx.x;
  int pt = blk % 36; int t2 = blk / 36; int r = t2 & 7, b = t2 >> 3;
  int p0 = pt * 64;
  int ybase = p0 / 48;
  int tid = threadIdx.x;
  for (int idx = tid; idx < TDW; idx += 256) {
    int ty = idx / 88, tx = idx - ty * 88;
    int gy = ybase + ty - 8, gx = tx - 8;
    float v = 0.f;
    if (gy >= 0 && gy < 64 && gx >= 0 && gx < 64) v = x[(b * 64 + gy) * 64 + gx];
    unsigned short h = (unsigned short)f2bf(v);
    lA[idx] = h;
    if (idx > 0) lB[idx - 1] = h;
  }
  if (tid == 0) lB[TDW - 1] = 0;
  __syncthreads();

  int lane = tid & 63, w = tid >> 6;
  int wm = w >> 1, wn = w & 1;
  int kc = lane >> 4;
  int ln = lane & 15;
  int mloc[2];
#pragma unroll
  for (int mf = 0; mf < 2; ++mf) {
    int p = p0 + wm * 32 + mf + 2 * ln;     // frag mf covers parity-mf pixels
    int ym = p / 48, xm = p - ym * 48;
    mloc[mf] = (ym - ybase) * 88 + xm;
  }
  const short* bb = bfrag + (size_t)r * (55 * 4 * 128 * 8);
  int nb0 = wn * 64;

  f32x4 acc33[2][4];
#pragma unroll
  for (int mf = 0; mf < 2; ++mf)
#pragma unroll
    for (int nf = 0; nf < 4; ++nf) acc33[mf][nf] = (f32x4){0.f, 0.f, 0.f, 0.f};

#define LOADB(dst, cg)                                                          \
  {                                                                             \
    _Pragma("unroll")                                                           \
    for (int nf = 0; nf < 4; ++nf)                                              \
      dst[nf] = *(const bf16x8*)(bb + ((size_t)((cg)*4 + kc) * 128 + nb0 + nf * 16 + ln) * 8); \
  }
#define READA(dst, mf, vv)                                                      \
  {                                                                             \
    int bd_ = ((vv) >> 1) + ((mf) ? SHW : 0);                                   \
    u32x4 uv_ = {lds[bd_], lds[bd_ + 1], lds[bd_ + 2], lds[bd_ + 3]};           \
    dst = __builtin_bit_cast(bf16x8, uv_);                                      \
  }

  // ---- phase 1: 33x33 kernel (rows padded to 40 taps, 42 K-steps) ----
  {
    int dxb = 8 * kc;
    int off = dxb;
    bf16x8 bc[4], bn[4];
    LOADB(bc, 0);
    for (int c = 0; c < NS33; ++c) {
      if (c + 1 < NS33) LOADB(bn, c + 1);
      bf16x8 a0, a1;
      READA(a0, 0, mloc[0] + off);
      READA(a1, 1, mloc[1] + off);
#pragma unroll
      for (int nf = 0; nf < 4; ++nf) {
        acc33[0][nf] = __builtin_amdgcn_mfma_f32_16x16x32_bf16(a0, bc[nf], acc33[0][nf], 0, 0, 0);
        acc33[1][nf] = __builtin_amdgcn_mfma_f32_16x16x32_bf16(a1, bc[nf], acc33[1][nf], 0, 0, 0);
      }
#pragma unroll
      for (int nf = 0; nf < 4; ++nf) bc[nf] = bn[nf];
      int nd = dxb + 32;
      int wr = (nd >= 40);
      dxb = wr ? nd - 40 : nd;
      off += wr ? 80 : 32;
    }
  }

  // ---- phase 2: 17x17 kernel (rows padded to 24 taps, 13 K-steps) ----
  f32x4 acc17[2][4];
#pragma unroll
  for (int mf = 0; mf < 2; ++mf)
#pragma unroll
    for (int nf = 0; nf < 4; ++nf) acc17[mf][nf] = (f32x4){0.f, 0.f, 0.f, 0.f};
  {
    int t8 = 8 * kc;
    int dy0 = t8 / 24;
    int dxb = t8 - 24 * dy0;
    int off = (8 + dy0) * 88 + 8 + dxb;
    for (int c = 0; c < NS17; ++c) {
      bf16x8 bc[4];
      LOADB(bc, NS33 + c);
      bf16x8 a0, a1;
      READA(a0, 0, mloc[0] + off);
      READA(a1, 1, mloc[1] + off);
#pragma unroll
      for (int nf = 0; nf < 4; ++nf) {
        acc17[0][nf] = __builtin_amdgcn_mfma_f32_16x16x32_bf16(a0, bc[nf], acc17[0][nf], 0, 0, 0);
        acc17[1][nf] = __builtin_amdgcn_mfma_f32_16x16x32_bf16(a1, bc[nf], acc17[1][nf], 0, 0, 0);
      }
      int nd = dxb + 8;
      int wr = (nd >= 24);
      dxb = wr ? nd - 24 : nd;
      off += wr ? 160 : 96;
    }
  }
#undef LOADB
#undef READA

  // ---- epilogue: bias, lrelu, alpha-combine -> LDS (swizzled) -> linear store ----
  __syncthreads();                       // all tile reads done; reuse LDS
  unsigned short* sOut = (unsigned short*)lds;   // [px][136] shorts, XOR-swizzled
  float a0s = scal[0], a1s = scal[1];
#pragma unroll
  for (int nf = 0; nf < 4; ++nf) {
    int n = nb0 + nf * 16 + ln;
    float bb17 = b17[n], bb33 = b33[n];
    int sw = n ^ (kc << 4);              // flip short bits 4,5 (dword bits 3,4)
#pragma unroll
    for (int mf = 0; mf < 2; ++mf) {
#pragma unroll
      for (int i = 0; i < 4; ++i) {
        int px = wm * 32 + mf + 8 * kc + 2 * i;
        float v = a0s * lrelu_f(acc17[mf][nf][i] + bb17)
                + a1s * lrelu_f(acc33[mf][nf][i] + bb33);
        sOut[px * 136 + sw] = (unsigned short)f2bf(v);
      }
    }
  }
  __syncthreads();
  size_t gbase = ((size_t)(b * 8 + r) * 2304 + p0) * 128;
#pragma unroll
  for (int pass = 0; pass < 4; ++pass) {
    int L16 = pass * 256 + tid;          // 16B-unit index, 0..1023
    int px = L16 >> 4, u = L16 & 15;
    int kc3 = (px >> 3) & 3;
    int pu = u ^ (kc3 << 1);             // inverse swizzle (dword bits 3,4)
    const unsigned int* lp = lds + px * 68 + pu * 4;
    u32x4 vv = {lp[0], lp[1], lp[2], lp[3]};
    *(u32x4*)(xoutb + gbase + (size_t)L16 * 8) = vv;
  }
}

// ---------------- MFMA 1x1 conv + fused heads, coalesced stores via LDS ----------------
// blocks [0,1152): i=0 (nR=4, rstep=2); [1152,3456): i=1 (nR=8, rstep=1)
__global__ __launch_bounds__(256, 4) void k_pw_mfma(
    const short* __restrict__ xoutb, const short* __restrict__ w2b_,
    const float* __restrict__ b2_, const float* __restrict__ wa_,
    const float* __restrict__ ba_, const float* __restrict__ wz_,
    const float* __restrict__ bz_,
    float* __restrict__ a0buf, float* __restrict__ z0buf,
    float* __restrict__ a1buf, float* __restrict__ z1buf) {
  __shared__ float sA[64];
  __shared__ float sZ[4][64];
  int blk = blockIdx.x;
  int i1 = (blk >= 1152);
  int lblk = i1 ? blk - 1152 : blk;
  int nR = i1 ? 8 : 4, rstep = i1 ? 1 : 2;
  const short* w2b = w2b_ + (i1 ? 128 * 128 : 0);
  const float* b2 = b2_ + (i1 ? 128 : 0);
  const float* wa = wa_ + (i1 ? 128 : 0);
  const float* ba = ba_ + i1;
  const float* wz = wz_ + (i1 ? 512 : 0);
  const float* bz = bz_ + (i1 ? 4 : 0);
  float* attn_out = i1 ? a1buf : a0buf;
  float* z_out = i1 ? z1buf : z0buf;

  int pblk = lblk % 36;
  int t = lblk / 36;
  int rl = t % nR;
  int b = t / nR;
  int pix0 = pblk * 64;
  int tid = threadIdx.x;
  int lane = tid & 63, w = tid >> 6;
  int kc = lane >> 4, ln = lane & 15;
  int pwave = pix0 + w * 16;
  const short* arow = xoutb + ((size_t)(b * 8 + rl * rstep) * 2304 + pwave) * 128;

  f32x4 acc[8];
#pragma unroll
  for (int nf = 0; nf < 8; ++nf) acc[nf] = (f32x4){0.f, 0.f, 0.f, 0.f};
#pragma unroll
  for (int s = 0; s < 4; ++s) {
    bf16x8 a = *(const bf16x8*)(arow + ln * 128 + s * 32 + kc * 8);
#pragma unroll
    for (int nf = 0; nf < 8; ++nf) {
      bf16x8 bv = *(const bf16x8*)(w2b + (nf * 16 + ln) * 128 + s * 32 + kc * 8);
      acc[nf] = __builtin_amdgcn_mfma_f32_16x16x32_bf16(a, bv, acc[nf], 0, 0, 0);
    }
  }

  float attn_acc[4] = {0.f, 0.f, 0.f, 0.f};
  float zacc[4][4];
#pragma unroll
  for (int j = 0; j < 4; ++j)
#pragma unroll
    for (int q = 0; q < 4; ++q) zacc[j][q] = 0.f;
#pragma unroll
  for (int nf = 0; nf < 8; ++nf) {
    int n = nf * 16 + ln;
    float bb2 = b2[n];
    float wan = wa[n];
    float wz0 = wz[n], wz1 = wz[128 + n], wz2 = wz[256 + n], wz3 = wz[384 + n];
#pragma unroll
    for (int q = 0; q < 4; ++q) {
      float h = lrelu_f(acc[nf][q] + bb2);
      attn_acc[q] = fmaf(wan, h, attn_acc[q]);
      zacc[0][q] = fmaf(wz0, h, zacc[0][q]);
      zacc[1][q] = fmaf(wz1, h, zacc[1][q]);
      zacc[2][q] = fmaf(wz2, h, zacc[2][q]);
      zacc[3][q] = fmaf(wz3, h, zacc[3][q]);
    }
  }
#pragma unroll
  for (int off = 1; off < 16; off <<= 1) {
#pragma unroll
    for (int q = 0; q < 4; ++q) {
      attn_acc[q] += __shfl_xor(attn_acc[q], off);
#pragma unroll
      for (int j = 0; j < 4; ++j) zacc[j][q] += __shfl_xor(zacc[j][q], off);
    }
  }
  if (ln == 0) {
    float ba0 = ba[0];
#pragma unroll
    for (int q = 0; q < 4; ++q) {
      int px = w * 16 + kc * 4 + q;
      sA[px] = attn_acc[q] + ba0;
#pragma unroll
      for (int j = 0; j < 4; ++j) sZ[j][px] = zacc[j][q] + bz[j];
    }
  }
  __syncthreads();
  int px = tid & 63, jj = tid >> 6;
  if (jj == 0)
    attn_out[((size_t)b * nR + rl) * 2304 + pix0 + px] = sA[px];
  z_out[(((size_t)b * 4 + jj) * nR + rl) * 2304 + pix0 + px] = sZ[jj][px];
}

// ---------------- attn scatter + p_r; also p_r / offsets outputs ----------------
__global__ void k_attn_combine(const float* __restrict__ a0buf, const float* __restrict__ a1buf,
                               const float* __restrict__ scal, float* __restrict__ out0,
                               float* __restrict__ out2, float* __restrict__ out4) {
  int idx = blockIdx.x * blockDim.x + threadIdx.x;
  if (idx < 8) {
    float off = off_r(idx);
    out4[idx] = off;
    float q = off / (float)PI_D;
    out2[idx] = -0.5f * q * q - logf((float)PI_D) - 0.5f * logf(2.0f * (float)PI_D);
  }
  if (idx >= 147456) return;
  int pix = idx % 2304;
  int t = idx / 2304;
  int r = t & 7, b = t >> 3;
  float v = scal[3] * a1buf[idx];
  if (!(r & 1)) v += scal[2] * a0buf[((size_t)b * 4 + (r >> 1)) * 2304 + pix];
  float q = off_r(r) / (float)PI_D;
  v += -0.5f * q * q - logf((float)PI_D) - 0.5f * logf(2.0f * (float)PI_D);
  out0[idx] = v;
}

// ---------------- per-batch softmax / log_softmax over 18432 ----------------
__global__ __launch_bounds__(1024) void k_softmax(const float* __restrict__ out0,
                                                  const float* __restrict__ g,
                                                  float* __restrict__ out1,
                                                  float* __restrict__ out3) {
  int b = blockIdx.x;
  int tid = threadIdx.x;
  const float* v = out0 + (size_t)b * 18432;
  const float* gb = g + (size_t)b * 18432;
  float vl[18], gl[18];
  float m1 = -1e30f, m2 = -1e30f;
#pragma unroll
  for (int t = 0; t < 18; ++t) {
    float vv = v[tid + (t << 10)];
    float gg = gb[tid + (t << 10)];
    vl[t] = vv;
    gl[t] = vv + gg;
    m1 = fmaxf(m1, vv);
    m2 = fmaxf(m2, gl[t]);
  }
  __shared__ float red[32];
  for (int off = 32; off > 0; off >>= 1) {
    m1 = fmaxf(m1, __shfl_xor(m1, off));
    m2 = fmaxf(m2, __shfl_xor(m2, off));
  }
  int wid = tid >> 6, lane = tid & 63;
  if (lane == 0) { red[wid] = m1; red[wid + 16] = m2; }
  __syncthreads();
  float M1 = red[0], M2 = red[16];
#pragma unroll
  for (int w = 1; w < 16; ++w) { M1 = fmaxf(M1, red[w]); M2 = fmaxf(M2, red[w + 16]); }
  __syncthreads();
  float s1 = 0.f, s2 = 0.f;
#pragma unroll
  for (int t = 0; t < 18; ++t) { s1 += expf(vl[t] - M1); s2 += expf(gl[t] - M2); }
  for (int off = 32; off > 0; off >>= 1) {
    s1 += __shfl_xor(s1, off);
    s2 += __shfl_xor(s2, off);
  }
  if (lane == 0) { red[wid] = s1; red[wid + 16] = s2; }
  __syncthreads();
  float S1 = 0.f, S2 = 0.f;
#pragma unroll
  for (int w = 0; w < 16; ++w) { S1 += red[w]; S2 += red[w + 16]; }
  float lse = M1 + logf(S1);
  float inv2 = 1.0f / S2;
  float* o1 = out1 + (size_t)b * 18432;
  float* o3 = out3 + (size_t)b * 18432;
#pragma unroll
  for (int t = 0; t < 18; ++t) {
    o1[tid + (t << 10)] = vl[t] - lse;
    o3[tid + (t << 10)] = expf(gl[t] - M2) * inv2;
  }
}

// ---------------- z scatter + theta ----------------
__global__ void k_ztheta(const float* __restrict__ z0buf, const float* __restrict__ z1buf,
                         const float* __restrict__ scal, float* __restrict__ out5,
                         float* __restrict__ out6) {
  int idx = blockIdx.x * blockDim.x + threadIdx.x;
  if (idx >= 589824) return;
  int pix = idx % 2304;
  int t = idx / 2304;
  int r = t & 7;
  t >>= 3;
  int c = t & 3;
  int b = t >> 2;
  float v = scal[3] * z1buf[idx];
  if (!(r & 1)) v += scal[2] * z0buf[(((size_t)b * 4 + c) * 4 + (r >> 1)) * 2304 + pix];
  out6[idx] = v;
  if (c == 0)      out5[(((size_t)b * 2 + 0) * 8 + r) * 2304 + pix] = v + off_r(r);
  else if (c == 1) out5[(((size_t)b * 2 + 1) * 8 + r) * 2304 + pix] = v;
}

// ---------------- launcher ----------------
extern "C" void kernel_launch(void* const* d_in, const int* in_sizes, int n_in,
                              void* d_out, int out_size, void* d_ws, size_t ws_size,
                              hipStream_t stream) {
  const float* x   = (const float*)d_in[0];
  const float* ksz = (const float*)d_in[1];
  const float* rdw = (const float*)d_in[2];
  const float* w0  = (const float*)d_in[3];
  const float* b0  = (const float*)d_in[4];
  const float* w1  = (const float*)d_in[5];
  const float* b1  = (const float*)d_in[6];
  const float* w2  = (const float*)d_in[7];
  const float* b2  = (const float*)d_in[8];
  const float* wa  = (const float*)d_in[9];
  const float* ba  = (const float*)d_in[10];
  const float* wz  = (const float*)d_in[11];
  const float* bz  = (const float*)d_in[12];
  const float* gks = (const float*)d_in[13];
  const float* grd = (const float*)d_in[14];
  const float* gat = (const float*)d_in[15];
  float* out = (float*)d_out;
  float* ws  = (float*)d_ws;

  float* scal = ws + OFF_SCAL;
  float* w0T  = ws + OFF_W0T;
  float* w1T  = ws + OFF_W1T;
  short* w2b  = (short*)(ws + OFF_W2B);
  short* bfr  = (short*)(ws + OFF_BF);
  short* xoutb = (short*)(ws + OFF_XOUTB);
  float* a0b  = ws + OFF_A0;
  float* a1b  = ws + OFF_A1;
  float* z0b  = ws + OFF_Z0;
  float* z1b  = ws + OFF_Z1;

  float* out0 = out;
  float* out1 = out + 147456;
  float* out2 = out + 294912;
  float* out3 = out + 294920;
  float* out4 = out + 442376;
  float* out5 = out + 442384;
  float* out6 = out + 737296;

  k_prep1<<<817, 256, 0, stream>>>(ksz, gks, rdw, grd, w0, w1, w2, scal, w0T, w1T, w2b);
  k_prep2<<<880, 256, 0, stream>>>(w0T, w1T, bfr);
  k_conv_mfma<<<2304, 256, 0, stream>>>(x, bfr, b0, b1, scal, xoutb);
  k_pw_mfma<<<3456, 256, 0, stream>>>(xoutb, w2b, b2, wa, ba, wz, bz,
                                      a0b, z0b, a1b, z1b);
  k_attn_combine<<<576, 256, 0, stream>>>(a0b, a1b, scal, out0, out2, out4);
  k_softmax<<<8, 1024, 0, stream>>>(out0, gat, out1, out3);
  k_ztheta<<<2304, 256, 0, stream>>>(z0b, z1b, scal, out5, out6);
}

// Round 9
// 256.761 us; speedup vs baseline: 1.2318x; 1.0418x over previous
//
#include <hip/hip_runtime.h>
#include <hip/hip_bf16.h>
#include <math.h>

#define PI_D 3.14159265358979323846

typedef __attribute__((ext_vector_type(8))) short bf16x8;
typedef __attribute__((ext_vector_type(4))) float f32x4;
typedef __attribute__((ext_vector_type(4))) unsigned int u32x4;

// ---------------- workspace layout (float offsets) ----------------
#define OFF_SCAL   0u                 // 4 floats
#define OFF_W0T    4u                 // 289*128
#define OFF_W1T    36996u             // 1089*128
#define OFF_W2B    176388u            // 2*128*128 bf16 = 16384 floats [i][o'][k]
#define OFF_BF     192772u            // Bfrag: 8r*55c*4kb*128o*8j bf16 = 901120 floats
#define OFF_XOUTB  1093892u           // 8*8*2304*128 bf16 = 9437184 floats (18.9M shorts)
#define OFF_A0     10531076u          // 8*4*2304
#define OFF_A1     10604804u          // 8*8*2304
#define OFF_Z0     10752260u          // 8*4*4*2304
#define OFF_Z1     11047172u          // 8*4*8*2304 -> ends 11636996 floats = 46.5 MB

#define NS33 42                       // K-steps for 33-kernel (165 units of 8 taps + 3 dummy)
#define NS17 13                       // K-steps for 17-kernel (51 units + 1 dummy)

__device__ __forceinline__ float off_r(int r) {
  int m = (r <= 4) ? r : r - 8;
  return (float)(PI_D / 4.0) * (float)m;
}
__device__ __forceinline__ float lrelu_f(float v) { return (v >= 0.f) ? v : 0.01f * v; }
__device__ __forceinline__ short f2bf(float f) {
  __bf16 h = (__bf16)f;
  return __builtin_bit_cast(short, h);
}

// K-unit -> (row dy, 8-px chunk ch). Units walk even rows (stride 2) then odd:
// within a K-step the 4 kc units sit in rows dy,dy+2,dy+4,dy+6 -> LDS bank
// shifts {0,24,16,8} mod 32 -> exact 2-way aliasing (free).
__device__ __forceinline__ void unit33(int u, int& dy, int& ch) {
  if (u < 85)       { dy = (u % 17) * 2;            ch = u / 17; }
  else if (u < 165) { int v = u - 85; dy = (v & 15) * 2 + 1; ch = v >> 4; }
  else              { dy = 33; ch = 0; }            // dummy (zero weight)
}
__device__ __forceinline__ void unit17(int u, int& dy, int& ch) {
  if (u < 27)      { dy = (u % 9) * 2;             ch = u / 9; }
  else if (u < 51) { int v = u - 27; dy = (v & 7) * 2 + 1; ch = v >> 3; }
  else             { dy = 17; ch = 0; }             // dummy (zero weight)
}

// ---------------- prep1: scalars + coalesced transposes + w2 cast ----------------
__global__ void k_prep1(const float* __restrict__ kw, const float* __restrict__ gk,
                        const float* __restrict__ rw, const float* __restrict__ gr,
                        const float* __restrict__ w0, const float* __restrict__ w1,
                        const float* __restrict__ w2, float* __restrict__ scal,
                        float* __restrict__ w0T, float* __restrict__ w1T,
                        short* __restrict__ w2b) {
  int idx = blockIdx.x * blockDim.x + threadIdx.x;
  if (idx == 0) {
    float a0 = (kw[0] + gk[0]) * 0.1f, a1 = (kw[1] + gk[1]) * 0.1f;
    float m = fmaxf(a0, a1);
    float e0 = expf(a0 - m), e1 = expf(a1 - m), inv = 1.f / (e0 + e1);
    scal[0] = e0 * inv; scal[1] = e1 * inv;
    float b0 = (rw[0] + gr[0]) * 0.1f, b1 = (rw[1] + gr[1]) * 0.1f;
    m = fmaxf(b0, b1);
    e0 = expf(b0 - m); e1 = expf(b1 - m); inv = 1.f / (e0 + e1);
    scal[2] = e0 * inv; scal[3] = e1 * inv;
  }
  if (idx < 289 * 128) {
    int o = idx & 127, pos = idx >> 7;
    w0T[pos * 128 + o] = w0[o * 289 + pos];
    return;
  }
  idx -= 289 * 128;
  if (idx < 1089 * 128) {
    int o = idx & 127, pos = idx >> 7;
    w1T[pos * 128 + o] = w1[o * 1089 + pos];
    return;
  }
  idx -= 1089 * 128;
  if (idx < 2 * 128 * 128) w2b[idx] = f2bf(w2[idx]);   // [i][o'][k]
}

// ---------------- prep2: fused rotation + B-fragment build ----------------
__global__ void k_prep2(const float* __restrict__ w0T, const float* __restrict__ w1T,
                        short* __restrict__ bfrag) {
  int t = blockIdx.x * blockDim.x + threadIdx.x;   // 225280 threads
  int o = t & 127;
  int q = t >> 7;
  int kb = q & 3; q >>= 2;
  int c = q % 55; int r = q / 55;
  float theta = (float)(PI_D / 4.0) * (float)r;
  float cth = cosf(theta), sth = sinf(theta);
  short out[8];
#pragma unroll
  for (int j = 0; j < 8; ++j) {
    float val = 0.f;
    int k, dy, ch;
    const float* wT;
    if (c < NS33) { unit33(4 * c + kb, dy, ch); k = 33; wT = w1T; }
    else          { unit17(4 * (c - NS33) + kb, dy, ch); k = 17; wT = w0T; }
    int dx = 8 * ch + j;
    if (dy < k && dx < k) {
      float cy = (2.0f * (float)dy + 1.0f) / (float)k - 1.0f;
      float cx = (2.0f * (float)dx + 1.0f) / (float)k - 1.0f;
      float sx = cth * cx - sth * cy;
      float sy = sth * cx + cth * cy;
      float fx = ((sx + 1.0f) * (float)k - 1.0f) * 0.5f;
      float fy = ((sy + 1.0f) * (float)k - 1.0f) * 0.5f;
      float x0f = floorf(fx), y0f = floorf(fy);
      int x0 = (int)x0f, y0 = (int)y0f;
      float wx1 = fx - x0f, wy1 = fy - y0f;
      float acc = 0.f;
#define CORNER(Y, X, CW) { int yy = (Y), xx = (X); \
      if (yy >= 0 && yy < k && xx >= 0 && xx < k) acc += wT[(yy * k + xx) * 128 + o] * (CW); }
      CORNER(y0,     x0,     (1.f - wy1) * (1.f - wx1));
      CORNER(y0,     x0 + 1, (1.f - wy1) * wx1);
      CORNER(y0 + 1, x0,     wy1 * (1.f - wx1));
      CORNER(y0 + 1, x0 + 1, wy1 * wx1);
#undef CORNER
      val = acc;
    }
    out[j] = f2bf(val);
  }
  *(bf16x8*)(bfrag + (size_t)t * 8) =
      (bf16x8){out[0], out[1], out[2], out[3], out[4], out[5], out[6], out[7]};
}

// ---------------- MFMA implicit-GEMM conv, M=128/block, XCD-swizzled ----------------
// grid 1152: r = blk&7 (XCD-resident bfrag slice), q=blk>>3: pt=q%18, b=q/18.
// bf16 LDS tile (37 rows x 88), two copies (copyB = shift-by-1-pixel), fragments
// parity-mapped; row-strided K-units -> 2-way-max LDS banking. Epilogue staged
// in LDS (kc-XOR swizzle) -> linear 32 KB contiguous store.
#define TDW 3256                      // 37 rows x 88 cols (pixels/shorts)
#define LBOFF 1628                    // copyB dword offset (= TDW/2)
__global__ __launch_bounds__(256, 2) void k_conv_mfma(
    const float* __restrict__ x, const short* __restrict__ bfrag,
    const float* __restrict__ b17, const float* __restrict__ b33,
    const float* __restrict__ scal, short* __restrict__ xoutb) {
  __shared__ __align__(16) unsigned int lds[8704];        // 34816 B
  unsigned short* lA = (unsigned short*)lds;              // pixel i at idx i
  unsigned short* lB = (unsigned short*)(lds + LBOFF);    // pixel i+1 at idx i
  int blk = blockIdx.x;
  int r = blk & 7;
  int q = blk >> 3;
  int pt = q % 18, b = q / 18;
  int p0 = pt * 128;
  int ybase = p0 / 48;
  int tid = threadIdx.x;
  for (int idx = tid; idx < TDW; idx += 256) {
    int ty = idx / 88, tx = idx - ty * 88;
    int gy = ybase + ty - 8, gx = tx - 8;
    float v = 0.f;
    if (gy >= 0 && gy < 64 && gx >= 0 && gx < 64) v = x[(b * 64 + gy) * 64 + gx];
    unsigned short h = (unsigned short)f2bf(v);
    lA[idx] = h;
    if (idx > 0) lB[idx - 1] = h;
  }
  if (tid == 0) lB[TDW - 1] = 0;
  __syncthreads();

  int lane = tid & 63, w = tid >> 6;
  int wm = w >> 1, wn = w & 1;
  int kc = lane >> 4;
  int ln = lane & 15;
  int mloc[4];
#pragma unroll
  for (int mf = 0; mf < 4; ++mf) {
    int p = p0 + wm * 64 + (mf >> 1) * 32 + (mf & 1) + 2 * ln;
    int ym = p / 48, xm = p - ym * 48;
    mloc[mf] = (ym - ybase) * 88 + xm;
  }
  const short* bb = bfrag + (size_t)r * (55 * 4 * 128 * 8);
  int nb0 = wn * 64;

  f32x4 acc33[4][4];
#pragma unroll
  for (int mf = 0; mf < 4; ++mf)
#pragma unroll
    for (int nf = 0; nf < 4; ++nf) acc33[mf][nf] = (f32x4){0.f, 0.f, 0.f, 0.f};

#define LOADB(dst, cg)                                                          \
  {                                                                             \
    _Pragma("unroll")                                                           \
    for (int nf = 0; nf < 4; ++nf)                                              \
      dst[nf] = *(const bf16x8*)(bb + ((size_t)((cg)*4 + kc) * 128 + nb0 + nf * 16 + ln) * 8); \
  }
#define READA(dst, par, vv)                                                     \
  {                                                                             \
    int bd_ = ((vv) >> 1) + ((par) ? LBOFF : 0);                                \
    u32x4 uv_ = {lds[bd_], lds[bd_ + 1], lds[bd_ + 2], lds[bd_ + 3]};           \
    dst = __builtin_bit_cast(bf16x8, uv_);                                      \
  }

  // ---- phase 1: 33x33 kernel, 42 K-steps ----
  {
    bf16x8 bc[4], bn[4];
    LOADB(bc, 0);
    for (int c = 0; c < NS33; ++c) {
      if (c + 1 < NS33) LOADB(bn, c + 1);
      int dy, ch;
      unit33(4 * c + kc, dy, ch);
      int off = dy * 88 + ch * 8;
      bf16x8 a[4];
      READA(a[0], 0, mloc[0] + off);
      READA(a[1], 1, mloc[1] + off);
      READA(a[2], 0, mloc[2] + off);
      READA(a[3], 1, mloc[3] + off);
#pragma unroll
      for (int nf = 0; nf < 4; ++nf) {
#pragma unroll
        for (int mf = 0; mf < 4; ++mf)
          acc33[mf][nf] = __builtin_amdgcn_mfma_f32_16x16x32_bf16(a[mf], bc[nf], acc33[mf][nf], 0, 0, 0);
      }
#pragma unroll
      for (int nf = 0; nf < 4; ++nf) bc[nf] = bn[nf];
    }
  }

  // ---- phase 2: 17x17 kernel, 13 K-steps ----
  f32x4 acc17[4][4];
#pragma unroll
  for (int mf = 0; mf < 4; ++mf)
#pragma unroll
    for (int nf = 0; nf < 4; ++nf) acc17[mf][nf] = (f32x4){0.f, 0.f, 0.f, 0.f};
  for (int c = 0; c < NS17; ++c) {
    bf16x8 bc[4];
    LOADB(bc, NS33 + c);
    int dy, ch;
    unit17(4 * c + kc, dy, ch);
    int off = (8 + dy) * 88 + 8 + ch * 8;
    bf16x8 a[4];
    READA(a[0], 0, mloc[0] + off);
    READA(a[1], 1, mloc[1] + off);
    READA(a[2], 0, mloc[2] + off);
    READA(a[3], 1, mloc[3] + off);
#pragma unroll
    for (int nf = 0; nf < 4; ++nf) {
#pragma unroll
      for (int mf = 0; mf < 4; ++mf)
        acc17[mf][nf] = __builtin_amdgcn_mfma_f32_16x16x32_bf16(a[mf], bc[nf], acc17[mf][nf], 0, 0, 0);
    }
  }
#undef LOADB
#undef READA

  // ---- epilogue: bias, lrelu, alpha-combine -> LDS (swizzled) -> linear store ----
  __syncthreads();                       // all tile reads done; reuse LDS
  unsigned short* sOut = (unsigned short*)lds;   // [px][136] shorts, XOR-swizzled
  float a0s = scal[0], a1s = scal[1];
#pragma unroll
  for (int nf = 0; nf < 4; ++nf) {
    int n = nb0 + nf * 16 + ln;
    float bb17 = b17[n], bb33 = b33[n];
    int sw = n ^ (kc << 4);              // flip short bits 4,5
#pragma unroll
    for (int mf = 0; mf < 4; ++mf) {
#pragma unroll
      for (int i = 0; i < 4; ++i) {
        int px = wm * 64 + (mf >> 1) * 32 + (mf & 1) + 8 * kc + 2 * i;
        float v = a0s * lrelu_f(acc17[mf][nf][i] + bb17)
                + a1s * lrelu_f(acc33[mf][nf][i] + bb33);
        sOut[px * 136 + sw] = (unsigned short)f2bf(v);
      }
    }
  }
  __syncthreads();
  size_t gbase = ((size_t)(b * 8 + r) * 2304 + p0) * 128;
#pragma unroll
  for (int pass = 0; pass < 8; ++pass) {
    int L16 = pass * 256 + tid;          // 16B-unit index, 0..2047
    int px = L16 >> 4, u = L16 & 15;
    int kc3 = (px >> 3) & 3;
    int pu = u ^ (kc3 << 1);             // inverse swizzle
    const unsigned int* lp = lds + px * 68 + pu * 4;
    u32x4 vv = {lp[0], lp[1], lp[2], lp[3]};
    *(u32x4*)(xoutb + gbase + (size_t)L16 * 8) = vv;
  }
}

// ---------------- MFMA 1x1 conv + fused heads, coalesced stores via LDS ----------------
// blocks [0,1152): i=0 (nR=4, rstep=2); [1152,3456): i=1 (nR=8, rstep=1)
__global__ __launch_bounds__(256, 4) void k_pw_mfma(
    const short* __restrict__ xoutb, const short* __restrict__ w2b_,
    const float* __restrict__ b2_, const float* __restrict__ wa_,
    const float* __restrict__ ba_, const float* __restrict__ wz_,
    const float* __restrict__ bz_,
    float* __restrict__ a0buf, float* __restrict__ z0buf,
    float* __restrict__ a1buf, float* __restrict__ z1buf) {
  __shared__ float sA[64];
  __shared__ float sZ[4][64];
  int blk = blockIdx.x;
  int i1 = (blk >= 1152);
  int lblk = i1 ? blk - 1152 : blk;
  int nR = i1 ? 8 : 4, rstep = i1 ? 1 : 2;
  const short* w2b = w2b_ + (i1 ? 128 * 128 : 0);
  const float* b2 = b2_ + (i1 ? 128 : 0);
  const float* wa = wa_ + (i1 ? 128 : 0);
  const float* ba = ba_ + i1;
  const float* wz = wz_ + (i1 ? 512 : 0);
  const float* bz = bz_ + (i1 ? 4 : 0);
  float* attn_out = i1 ? a1buf : a0buf;
  float* z_out = i1 ? z1buf : z0buf;

  int pblk = lblk % 36;
  int t = lblk / 36;
  int rl = t % nR;
  int b = t / nR;
  int pix0 = pblk * 64;
  int tid = threadIdx.x;
  int lane = tid & 63, w = tid >> 6;
  int kc = lane >> 4, ln = lane & 15;
  int pwave = pix0 + w * 16;
  const short* arow = xoutb + ((size_t)(b * 8 + rl * rstep) * 2304 + pwave) * 128;

  f32x4 acc[8];
#pragma unroll
  for (int nf = 0; nf < 8; ++nf) acc[nf] = (f32x4){0.f, 0.f, 0.f, 0.f};
#pragma unroll
  for (int s = 0; s < 4; ++s) {
    bf16x8 a = *(const bf16x8*)(arow + ln * 128 + s * 32 + kc * 8);
#pragma unroll
    for (int nf = 0; nf < 8; ++nf) {
      bf16x8 bv = *(const bf16x8*)(w2b + (nf * 16 + ln) * 128 + s * 32 + kc * 8);
      acc[nf] = __builtin_amdgcn_mfma_f32_16x16x32_bf16(a, bv, acc[nf], 0, 0, 0);
    }
  }

  float attn_acc[4] = {0.f, 0.f, 0.f, 0.f};
  float zacc[4][4];
#pragma unroll
  for (int j = 0; j < 4; ++j)
#pragma unroll
    for (int q = 0; q < 4; ++q) zacc[j][q] = 0.f;
#pragma unroll
  for (int nf = 0; nf < 8; ++nf) {
    int n = nf * 16 + ln;
    float bb2 = b2[n];
    float wan = wa[n];
    float wz0 = wz[n], wz1 = wz[128 + n], wz2 = wz[256 + n], wz3 = wz[384 + n];
#pragma unroll
    for (int q = 0; q < 4; ++q) {
      float h = lrelu_f(acc[nf][q] + bb2);
      attn_acc[q] = fmaf(wan, h, attn_acc[q]);
      zacc[0][q] = fmaf(wz0, h, zacc[0][q]);
      zacc[1][q] = fmaf(wz1, h, zacc[1][q]);
      zacc[2][q] = fmaf(wz2, h, zacc[2][q]);
      zacc[3][q] = fmaf(wz3, h, zacc[3][q]);
    }
  }
#pragma unroll
  for (int off = 1; off < 16; off <<= 1) {
#pragma unroll
    for (int q = 0; q < 4; ++q) {
      attn_acc[q] += __shfl_xor(attn_acc[q], off);
#pragma unroll
      for (int j = 0; j < 4; ++j) zacc[j][q] += __shfl_xor(zacc[j][q], off);
    }
  }
  if (ln == 0) {
    float ba0 = ba[0];
#pragma unroll
    for (int q = 0; q < 4; ++q) {
      int px = w * 16 + kc * 4 + q;
      sA[px] = attn_acc[q] + ba0;
#pragma unroll
      for (int j = 0; j < 4; ++j) sZ[j][px] = zacc[j][q] + bz[j];
    }
  }
  __syncthreads();
  int px = tid & 63, jj = tid >> 6;
  if (jj == 0)
    attn_out[((size_t)b * nR + rl) * 2304 + pix0 + px] = sA[px];
  z_out[(((size_t)b * 4 + jj) * nR + rl) * 2304 + pix0 + px] = sZ[jj][px];
}

// ---------------- attn scatter + p_r; also p_r / offsets outputs ----------------
__global__ void k_attn_combine(const float* __restrict__ a0buf, const float* __restrict__ a1buf,
                               const float* __restrict__ scal, float* __restrict__ out0,
                               float* __restrict__ out2, float* __restrict__ out4) {
  int idx = blockIdx.x * blockDim.x + threadIdx.x;
  if (idx < 8) {
    float off = off_r(idx);
    out4[idx] = off;
    float q = off / (float)PI_D;
    out2[idx] = -0.5f * q * q - logf((float)PI_D) - 0.5f * logf(2.0f * (float)PI_D);
  }
  if (idx >= 147456) return;
  int pix = idx % 2304;
  int t = idx / 2304;
  int r = t & 7, b = t >> 3;
  float v = scal[3] * a1buf[idx];
  if (!(r & 1)) v += scal[2] * a0buf[((size_t)b * 4 + (r >> 1)) * 2304 + pix];
  float q = off_r(r) / (float)PI_D;
  v += -0.5f * q * q - logf((float)PI_D) - 0.5f * logf(2.0f * (float)PI_D);
  out0[idx] = v;
}

// ---------------- per-batch softmax / log_softmax over 18432 ----------------
__global__ __launch_bounds__(1024) void k_softmax(const float* __restrict__ out0,
                                                  const float* __restrict__ g,
                                                  float* __restrict__ out1,
                                                  float* __restrict__ out3) {
  int b = blockIdx.x;
  int tid = threadIdx.x;
  const float* v = out0 + (size_t)b * 18432;
  const float* gb = g + (size_t)b * 18432;
  float vl[18], gl[18];
  float m1 = -1e30f, m2 = -1e30f;
#pragma unroll
  for (int t = 0; t < 18; ++t) {
    float vv = v[tid + (t << 10)];
    float gg = gb[tid + (t << 10)];
    vl[t] = vv;
    gl[t] = vv + gg;
    m1 = fmaxf(m1, vv);
    m2 = fmaxf(m2, gl[t]);
  }
  __shared__ float red[32];
  for (int off = 32; off > 0; off >>= 1) {
    m1 = fmaxf(m1, __shfl_xor(m1, off));
    m2 = fmaxf(m2, __shfl_xor(m2, off));
  }
  int wid = tid >> 6, lane = tid & 63;
  if (lane == 0) { red[wid] = m1; red[wid + 16] = m2; }
  __syncthreads();
  float M1 = red[0], M2 = red[16];
#pragma unroll
  for (int w = 1; w < 16; ++w) { M1 = fmaxf(M1, red[w]); M2 = fmaxf(M2, red[w + 16]); }
  __syncthreads();
  float s1 = 0.f, s2 = 0.f;
#pragma unroll
  for (int t = 0; t < 18; ++t) { s1 += expf(vl[t] - M1); s2 += expf(gl[t] - M2); }
  for (int off = 32; off > 0; off >>= 1) {
    s1 += __shfl_xor(s1, off);
    s2 += __shfl_xor(s2, off);
  }
  if (lane == 0) { red[wid] = s1; red[wid + 16] = s2; }
  __syncthreads();
  float S1 = 0.f, S2 = 0.f;
#pragma unroll
  for (int w = 0; w < 16; ++w) { S1 += red[w]; S2 += red[w + 16]; }
  float lse = M1 + logf(S1);
  float inv2 = 1.0f / S2;
  float* o1 = out1 + (size_t)b * 18432;
  float* o3 = out3 + (size_t)b * 18432;
#pragma unroll
  for (int t = 0; t < 18; ++t) {
    o1[tid + (t << 10)] = vl[t] - lse;
    o3[tid + (t << 10)] = expf(gl[t] - M2) * inv2;
  }
}

// ---------------- z scatter + theta ----------------
__global__ void k_ztheta(const float* __restrict__ z0buf, const float* __restrict__ z1buf,
                         const float* __restrict__ scal, float* __restrict__ out5,
                         float* __restrict__ out6) {
  int idx = blockIdx.x * blockDim.x + threadIdx.x;
  if (idx >= 589824) return;
  int pix = idx % 2304;
  int t = idx / 2304;
  int r = t & 7;
  t >>= 3;
  int c = t & 3;
  int b = t >> 2;
  float v = scal[3] * z1buf[idx];
  if (!(r & 1)) v += scal[2] * z0buf[(((size_t)b * 4 + c) * 4 + (r >> 1)) * 2304 + pix];
  out6[idx] = v;
  if (c == 0)      out5[(((size_t)b * 2 + 0) * 8 + r) * 2304 + pix] = v + off_r(r);
  else if (c == 1) out5[(((size_t)b * 2 + 1) * 8 + r) * 2304 + pix] = v;
}

// ---------------- launcher ----------------
extern "C" void kernel_launch(void* const* d_in, const int* in_sizes, int n_in,
                              void* d_out, int out_size, void* d_ws, size_t ws_size,
                              hipStream_t stream) {
  const float* x   = (const float*)d_in[0];
  const float* ksz = (const float*)d_in[1];
  const float* rdw = (const float*)d_in[2];
  const float* w0  = (const float*)d_in[3];
  const float* b0  = (const float*)d_in[4];
  const float* w1  = (const float*)d_in[5];
  const float* b1  = (const float*)d_in[6];
  const float* w2  = (const float*)d_in[7];
  const float* b2  = (const float*)d_in[8];
  const float* wa  = (const float*)d_in[9];
  const float* ba  = (const float*)d_in[10];
  const float* wz  = (const float*)d_in[11];
  const float* bz  = (const float*)d_in[12];
  const float* gks = (const float*)d_in[13];
  const float* grd = (const float*)d_in[14];
  const float* gat = (const float*)d_in[15];
  float* out = (float*)d_out;
  float* ws  = (float*)d_ws;

  float* scal = ws + OFF_SCAL;
  float* w0T  = ws + OFF_W0T;
  float* w1T  = ws + OFF_W1T;
  short* w2b  = (short*)(ws + OFF_W2B);
  short* bfr  = (short*)(ws + OFF_BF);
  short* xoutb = (short*)(ws + OFF_XOUTB);
  float* a0b  = ws + OFF_A0;
  float* a1b  = ws + OFF_A1;
  float* z0b  = ws + OFF_Z0;
  float* z1b  = ws + OFF_Z1;

  float* out0 = out;
  float* out1 = out + 147456;
  float* out2 = out + 294912;
  float* out3 = out + 294920;
  float* out4 = out + 442376;
  float* out5 = out + 442384;
  float* out6 = out + 737296;

  k_prep1<<<817, 256, 0, stream>>>(ksz, gks, rdw, grd, w0, w1, w2, scal, w0T, w1T, w2b);
  k_prep2<<<880, 256, 0, stream>>>(w0T, w1T, bfr);
  k_conv_mfma<<<1152, 256, 0, stream>>>(x, bfr, b0, b1, scal, xoutb);
  k_pw_mfma<<<3456, 256, 0, stream>>>(xoutb, w2b, b2, wa, ba, wz, bz,
                                      a0b, z0b, a1b, z1b);
  k_attn_combine<<<576, 256, 0, stream>>>(a0b, a1b, scal, out0, out2, out4);
  k_softmax<<<8, 1024, 0, stream>>>(out0, gat, out1, out3);
  k_ztheta<<<2304, 256, 0, stream>>>(z0b, z1b, scal, out5, out6);
}